// Round 8
// baseline (105.645 us; speedup 1.0000x reference)
//
#include <hip/hip_runtime.h>

#define BB 4
#define HH 1024
#define WW 1024
#define K2 9
#define PAD 1

#define R   12            // halo radius (covers ~6 sigma offsets)
#define TW  64            // tile width
#define TH  16            // tile height (4 rows per thread)
#define RW  (TW + 2*R)    // 88
#define RH  (TH + 2*R)    // 40
#define RSZ (RW * RH)     // 3520

__global__ __launch_bounds__(256) void dcn_kernel(
    const float* __restrict__ init_dem,   // [B,1,H,W]
    const float* __restrict__ weight,     // [B,K2,H,W]
    const float* __restrict__ offset,     // [B,2*K2,H,W]
    const float* __restrict__ wk,         // [K2]
    const float* __restrict__ bias,       // [1]
    float* __restrict__ out)              // [B,1,H,W]
{
    __shared__ float region[RSZ];

    const int HW = HH * WW;

    // batch pinned to an XCD pair (blockIdx % 8 -> XCD heuristic)
    int i    = blockIdx.x;
    int b    = (i & 7) >> 1;
    int widx = ((i >> 3) << 1) | (i & 1);     // 0 .. 1023, bijective
    int tile_w = widx & 15;                   // W/TW = 16
    int tile_h = widx >> 4;                   // H/TH = 64
    int w0 = tile_w * TW;
    int h0 = tile_h * TH;

    const float* img = init_dem + (size_t)b * HW;

    // ---- stage image region (halo included, zeros outside image) ----
    int tid = threadIdx.x;
#pragma unroll
    for (int it = 0; it < (RSZ + 255) / 256; ++it) {
        int e = tid + it * 256;
        if (e < RSZ) {
            int r = e / RW;
            int c = e - r * RW;
            int gy = h0 - R + r;
            int gx = w0 - R + c;
            float v = 0.f;
            if ((unsigned)gy < (unsigned)HH && (unsigned)gx < (unsigned)WW)
                v = img[gy * WW + gx];
            region[e] = v;
        }
    }
    __syncthreads();

    const int tx = tid & 63;
    const int ty = tid >> 6;
    const float bval = bias[0];

    float wgt[K2];
#pragma unroll
    for (int k = 0; k < K2; ++k) wgt[k] = wk[k];

#pragma unroll 2
    for (int p = 0; p < 4; ++p) {
        int h = h0 + ty + p * 4;
        int w = w0 + tx;
        int rem = h * WW + w;

        const float* wq = weight + (size_t)b * K2 * HW + rem;
        const float* oq = offset + (size_t)b * 2 * K2 * HW + rem;

        // batch all 27 stream loads for this row (kept in flight together)
        float wt[K2], dy[K2], dx[K2];
        float wsum = 0.f;
#pragma unroll
        for (int k = 0; k < K2; ++k) {
            wt[k] = __builtin_nontemporal_load(wq + (size_t)k * HW);
            dy[k] = __builtin_nontemporal_load(oq + (size_t)(2 * k) * HW);
            dx[k] = __builtin_nontemporal_load(oq + (size_t)(2 * k + 1) * HW);
            wsum += wt[k];
        }
        const float mean = wsum * (1.0f / K2);

        // local (region-space) coords: ysl = ys - (h0 - R), xsl = xs - (w0 - R)
        const float fy = (float)(ty + p * 4 + R - PAD);
        const float fx = (float)(tx + R - PAD);

        float acc = 0.f;
#pragma unroll
        for (int k = 0; k < K2; ++k) {
            const int ky = k / 3, kx = k % 3;

            float ysl = (fy + (float)ky) + dy[k];
            float xsl = (fx + (float)kx) + dx[k];

            float y0f = floorf(ysl);
            float x0f = floorf(xsl);
            float wy1 = ysl - y0f;
            float wx1 = xsl - x0f;
            float wy0 = 1.f - wy1;
            float wx0 = 1.f - wx1;

            int y0l = (int)y0f;
            int x0l = (int)x0f;

            float v00, v01, v10, v11;
            if (((unsigned)y0l < (unsigned)(RH - 1)) &
                ((unsigned)x0l < (unsigned)(RW - 1))) {
                int base = y0l * RW + x0l;
                v00 = region[base];
                v10 = region[base + RW];
                v01 = region[base + 1];
                v11 = region[base + RW + 1];
            } else {
                int y0g = y0l + (h0 - R);
                int x0g = x0l + (w0 - R);
                int y1g = y0g + 1;
                int x1g = x0g + 1;
                bool y0v = (y0g >= 0) & (y0g < HH);
                bool y1v = (y1g >= 0) & (y1g < HH);
                bool x0v = (x0g >= 0) & (x0g < WW);
                bool x1v = (x1g >= 0) & (x1g < WW);
                int yc0 = min(max(y0g, 0), HH - 1);
                int yc1 = min(max(y1g, 0), HH - 1);
                int xc0 = min(max(x0g, 0), WW - 1);
                int xc1 = min(max(x1g, 0), WW - 1);
                v00 = (y0v & x0v) ? img[(size_t)yc0 * WW + xc0] : 0.f;
                v01 = (y0v & x1v) ? img[(size_t)yc0 * WW + xc1] : 0.f;
                v10 = (y1v & x0v) ? img[(size_t)yc1 * WW + xc0] : 0.f;
                v11 = (y1v & x1v) ? img[(size_t)yc1 * WW + xc1] : 0.f;
            }

            float samp = wy0 * (wx0 * v00 + wx1 * v01)
                       + wy1 * (wx0 * v10 + wx1 * v11);
            acc += samp * (wt[k] - mean) * wgt[k];
        }

        float resid = region[(ty + p * 4 + R) * RW + (tx + R)];
        float rres  = acc + bval + resid;
        __builtin_nontemporal_store(rres, out + (size_t)b * HW + rem);
    }
}

extern "C" void kernel_launch(void* const* d_in, const int* in_sizes, int n_in,
                              void* d_out, int out_size, void* d_ws, size_t ws_size,
                              hipStream_t stream) {
    const float* init_dem = (const float*)d_in[0];
    const float* weight   = (const float*)d_in[1];
    const float* offset   = (const float*)d_in[2];
    const float* wk       = (const float*)d_in[3];
    const float* bias     = (const float*)d_in[4];
    float* out            = (float*)d_out;

    const int nblocks = BB * (WW / TW) * (HH / TH);   // 4*16*64 = 4096
    dcn_kernel<<<dim3(nblocks), dim3(256), 0, stream>>>(init_dem, weight, offset, wk, bias, out);
}